// Round 4
// baseline (253.482 us; speedup 1.0000x reference)
//
#include <hip/hip_runtime.h>
#include <math.h>

// Problem constants (B=2, T=2048, C=1024, H=16, hd=64)
#define B_  2
#define T_  2048
#define C_  1024
#define H_  16
#define HD_ 64

typedef __bf16 bf16x8 __attribute__((ext_vector_type(8)));
typedef float  f32x4  __attribute__((ext_vector_type(4)));

__device__ __forceinline__ unsigned short f2bf(float f) {
    unsigned int u = __float_as_uint(f);
    unsigned int r = (u + 0x7fffu + ((u >> 16) & 1u)) >> 16;   // RNE
    return (unsigned short)r;
}

// async global->LDS, 16B/lane. lds ptr must be WAVE-UNIFORM; HW adds lane*16.
__device__ __forceinline__ void async16(const void* g, void* l) {
    __builtin_amdgcn_global_load_lds(
        (const __attribute__((address_space(1))) unsigned int*)g,
        (__attribute__((address_space(3))) unsigned int*)l, 16, 0, 0);
}

// ---------------------------------------------------------------------------
// cast fp32 -> bf16, vectorized. n4 = n/4.
// ---------------------------------------------------------------------------
__global__ __launch_bounds__(256)
void castk(const float* __restrict__ in, unsigned short* __restrict__ out, int n4)
{
    const int i = blockIdx.x * 256 + threadIdx.x;
    if (i >= n4) return;
    const float4 v = ((const float4*)in)[i];
    ushort4 o;
    o.x = f2bf(v.x); o.y = f2bf(v.y); o.z = f2bf(v.z); o.w = f2bf(v.w);
    ((ushort4*)out)[i] = o;
}

// ---------------------------------------------------------------------------
// cast + transpose: in fp32 [K][N] -> out bf16 [N][K]. 32x32 LDS tiles.
// ---------------------------------------------------------------------------
__global__ __launch_bounds__(256)
void transcast_k(const float* __restrict__ in, unsigned short* __restrict__ out,
                 int K, int N)
{
    __shared__ float t[32][33];
    const int n0 = blockIdx.x * 32, k0 = blockIdx.y * 32;
    const int tx = threadIdx.x & 31, ty = threadIdx.x >> 5;
    #pragma unroll
    for (int r = 0; r < 4; ++r)
        t[ty + 8 * r][tx] = in[(size_t)(k0 + ty + 8 * r) * N + n0 + tx];
    __syncthreads();
    #pragma unroll
    for (int r = 0; r < 4; ++r)
        out[(size_t)(n0 + ty + 8 * r) * K + k0 + tx] = f2bf(t[tx][ty + 8 * r]);
}

// ---------------------------------------------------------------------------
// RoPE cos/sin table: tab[t*32+dd] = {cos(t*f_dd), sin(t*f_dd)}, fp32.
// ---------------------------------------------------------------------------
__global__ __launch_bounds__(256)
void rope_table_k(float2* __restrict__ tab)
{
    const int idx = blockIdx.x * 256 + threadIdx.x;   // 0 .. T_*32-1
    const int dd = idx & 31;
    const int t  = idx >> 5;
    const float invf = expf(-(float)dd * (9.210340371976184f / 32.0f)); // 10000^(-dd/32)
    float sn, cs;
    sincosf((float)t * invf, &sn, &cs);
    tab[idx] = make_float2(cs, sn);
}

// ---------------------------------------------------------------------------
// bf16 MFMA GEMM (m97 structure): 128x128 tile, BK=32, 4 waves (2x2 of 64x64),
// 4x4 mfma_f32_16x16x32_bf16 frags/wave, global_load_lds(16B) staging.
// A bf16 [M][K], Bt bf16 [N][K], bias fp32 [N].
// MODE 0: q,k bf16 [B,H,T,hd] with RoPE fused (rope = cos/sin table);
//         v bf16 [B,H,hd,T] (transposed scatter).
// MODE 1: out0 = fp32 [M][N].
// ---------------------------------------------------------------------------
template<int MODE>
__global__ __launch_bounds__(256)
void mgemm(const unsigned short* __restrict__ A, const unsigned short* __restrict__ Bt,
           const float* __restrict__ bias, const float2* __restrict__ rope,
           void* __restrict__ out0, void* __restrict__ out1, void* __restrict__ out2,
           int M, int N, int K)
{
    __shared__ __align__(16) unsigned short As[128 * 32];
    __shared__ __align__(16) unsigned short Bs[128 * 32];

    const int tid  = threadIdx.x;
    const int lane = tid & 63;
    const int wid  = tid >> 6;
    const int m0 = blockIdx.y * 128;
    const int n0 = blockIdx.x * 128;
    const int wr = wid >> 1, wc = wid & 1;

    const int srow = wid * 32 + (lane >> 2);
    const int scol = (lane & 3) * 8;
    const unsigned short* gA = A  + (size_t)(m0 + srow) * K + scol;
    const unsigned short* gB = Bt + (size_t)(n0 + srow) * K + scol;
    unsigned short* lA = As + wid * 1024;
    unsigned short* lB = Bs + wid * 1024;

    f32x4 acc[4][4];
    #pragma unroll
    for (int i = 0; i < 4; ++i)
        #pragma unroll
        for (int j = 0; j < 4; ++j) acc[i][j] = (f32x4)0.f;

    const int r15 = lane & 15;
    const int ko  = (lane >> 4) * 8;

    for (int kt = 0; kt < K; kt += 32) {
        __syncthreads();
        async16(gA + kt,          lA);
        async16(gA + kt + 16 * K, lA + 512);
        async16(gB + kt,          lB);
        async16(gB + kt + 16 * K, lB + 512);
        __syncthreads();

        bf16x8 af[4], bg[4];
        #pragma unroll
        for (int i = 0; i < 4; ++i)
            af[i] = *(const bf16x8*)(As + (wr * 64 + i * 16 + r15) * 32 + ko);
        #pragma unroll
        for (int j = 0; j < 4; ++j)
            bg[j] = *(const bf16x8*)(Bs + (wc * 64 + j * 16 + r15) * 32 + ko);
        #pragma unroll
        for (int i = 0; i < 4; ++i)
            #pragma unroll
            for (int j = 0; j < 4; ++j)
                acc[i][j] = __builtin_amdgcn_mfma_f32_16x16x32_bf16(af[i], bg[j], acc[i][j], 0, 0, 0);
    }

    // epilogue: C/D layout col=lane&15 (+j*16), row=(lane>>4)*4+reg  [m89]
    const int rg = (lane >> 4) * 4;
    if (MODE == 0) {
        const int which = n0 >> 10;               // block-uniform: 0=q 1=k 2=v
        if (which < 2) {
            // ---- fused RoPE on fp32 accumulators, single bf16 rounding ----
            unsigned short* dst = (unsigned short*)(which == 0 ? out0 : out1);
            const int h = ((n0 & 1023) >> 6) + wc;    // head (uniform per wave)
            #pragma unroll
            for (int i = 0; i < 4; ++i) {
                #pragma unroll
                for (int r = 0; r < 4; ++r) {
                    const int row = m0 + wr * 64 + i * 16 + rg + r;
                    const int b = row >> 11, t = row & 2047;
                    const size_t obase = (((size_t)(b * H_ + h)) * T_ + t) * HD_;
                    #pragma unroll
                    for (int j = 0; j < 2; ++j) {
                        const int d1 = j * 16 + r15;          // 0..31
                        const float v1 = acc[i][j][r]     + bias[n0 + wc * 64 + d1];
                        const float v2 = acc[i][j + 2][r] + bias[n0 + wc * 64 + d1 + 32];
                        const float2 cssn = rope[t * 32 + d1];
                        dst[obase + d1]      = f2bf(v1 * cssn.x - v2 * cssn.y);
                        dst[obase + d1 + 32] = f2bf(v2 * cssn.x + v1 * cssn.y);
                    }
                }
            }
        } else {
            // ---- v: bias + transpose-scatter to [B,H,hd,T] ----
            #pragma unroll
            for (int j = 0; j < 4; ++j) {
                const int col = n0 + wc * 64 + j * 16 + r15;
                const float bv = bias[col];
                const int c = col & 1023;
                const int h = c >> 6, d = c & 63;
                #pragma unroll
                for (int i = 0; i < 4; ++i) {
                    #pragma unroll
                    for (int r = 0; r < 4; ++r) {
                        const int row = m0 + wr * 64 + i * 16 + rg + r;
                        const int b = row >> 11, t = row & 2047;
                        ((unsigned short*)out2)[(((size_t)(b * H_ + h)) * HD_ + d) * T_ + t]
                            = f2bf(acc[i][j][r] + bv);
                    }
                }
            }
        }
    } else {
        #pragma unroll
        for (int j = 0; j < 4; ++j) {
            const int col = n0 + wc * 64 + j * 16 + r15;
            const float bv = bias[col];
            #pragma unroll
            for (int i = 0; i < 4; ++i) {
                #pragma unroll
                for (int r = 0; r < 4; ++r) {
                    const int row = m0 + wr * 64 + i * 16 + rg + r;
                    ((float*)out0)[(size_t)row * N + col] = acc[i][j][r] + bv;
                }
            }
        }
    }
}

// ---------------------------------------------------------------------------
// MFMA flash attention. Block = 4 waves, one (bh, 64-row q-tile).
// Q bf16 [B,H,T,hd] (in regs), K bf16 [B,H,T,hd], Vt bf16 [B,H,hd,T] (LDS,
// XOR-swizzled via pre-swizzled global_load_lds source). Y bf16 [B,T,C].
// Wave wid owns q-rows wid*16..+16. Per K-tile: 16 MFMA (8 QK^T + 8 PV).
// P reshaped through per-wave fp32 LDS [16][68] (same-wave in-order DS).
// ---------------------------------------------------------------------------
__global__ __launch_bounds__(256)
void attn_mfma(const unsigned short* __restrict__ Q,
               const unsigned short* __restrict__ K,
               const unsigned short* __restrict__ Vt,
               unsigned short* __restrict__ Y)
{
    __shared__ __align__(16) unsigned short Ks[64 * 64];   // 8KB, swizzled
    __shared__ __align__(16) unsigned short Vs[64 * 64];   // 8KB, swizzled (rows = d)
    __shared__ float Ps[4][16][68];                        // per-wave P, padded

    const int tid  = threadIdx.x;
    const int lane = tid & 63;
    const int wid  = tid >> 6;
    const int bh   = blockIdx.x;               // 0..31
    const int qt   = blockIdx.y;               // 0..31
    const int b    = bh >> 4, h = bh & 15;
    const int g    = lane >> 4;                // 0..3
    const int r15  = lane & 15;
    const int sw   = (r15 & 7) << 4;           // read-side XOR swizzle

    // staging: lane -> LDS row r0+(lane>>3), chunk lane&7;
    // source chunk = (lane&7) ^ (lane>>3)  [inverse of byte^=((row&7)<<4)]
    const int srow = lane >> 3;                // 0..7
    const int sch  = (lane & 7) ^ srow;
    const size_t qkbase = (size_t)bh * T_ * HD_;

    const unsigned short* gK0 = K  + qkbase + (size_t)(wid * 16 + srow) * HD_ + sch * 8;
    const unsigned short* gK1 = gK0 + 8 * HD_;
    const unsigned short* gV0 = Vt + ((size_t)bh * HD_ + wid * 16 + srow) * T_ + sch * 8;
    const unsigned short* gV1 = gV0 + (size_t)8 * T_;
    unsigned short* lK0 = Ks + (wid * 16) * HD_;
    unsigned short* lK1 = lK0 + 8 * HD_;
    unsigned short* lV0 = Vs + (wid * 16) * HD_;
    unsigned short* lV1 = lV0 + 8 * HD_;

    // Q fragments (A-operand): m = r15 (q-row), k = d
    const int qrow = qt * 64 + wid * 16 + r15;
    const unsigned short* qp = Q + qkbase + (size_t)qrow * HD_ + g * 8;
    const bf16x8 qf0 = *(const bf16x8*)(qp);
    const bf16x8 qf1 = *(const bf16x8*)(qp + 32);

    f32x4 po[4];
    float mrow[4], lrow[4];
    #pragma unroll
    for (int j = 0; j < 4; ++j) po[j] = (f32x4)0.f;
    #pragma unroll
    for (int r = 0; r < 4; ++r) { mrow[r] = -1e30f; lrow[r] = 0.f; }

    const int myrow = wid * 16 + g * 4;        // q-row (in tile) of acc reg r=0

    for (int kt = 0; kt <= qt; ++kt) {
        __syncthreads();                       // all waves done reading Ks/Vs
        async16(gK0 + (size_t)kt * 64 * HD_, lK0);
        async16(gK1 + (size_t)kt * 64 * HD_, lK1);
        async16(gV0 + kt * 64, lV0);
        async16(gV1 + kt * 64, lV1);
        __syncthreads();                       // vmcnt(0) drained: tiles ready

        // ---- S = Q K^T : B-frag from Ks[key][d] ----
        f32x4 sa[4];
        #pragma unroll
        for (int j = 0; j < 4; ++j) sa[j] = (f32x4)0.f;
        #pragma unroll
        for (int j = 0; j < 4; ++j) {
            const int kb0 = ((j * 16 + r15) * 128 + g * 16) ^ sw;
            const bf16x8 kf0 = *(const bf16x8*)((const char*)Ks + kb0);
            const bf16x8 kf1 = *(const bf16x8*)((const char*)Ks + (kb0 ^ 64));
            sa[j] = __builtin_amdgcn_mfma_f32_16x16x32_bf16(qf0, kf0, sa[j], 0, 0, 0);
            sa[j] = __builtin_amdgcn_mfma_f32_16x16x32_bf16(qf1, kf1, sa[j], 0, 0, 0);
        }

        // ---- online softmax (lane holds rows myrow+r, keys j*16+r15) ----
        const bool diag = (kt == qt);
        float p[4][4];
        #pragma unroll
        for (int r = 0; r < 4; ++r) {
            float sv[4];
            #pragma unroll
            for (int j = 0; j < 4; ++j) {
                sv[j] = sa[j][r] * 0.125f;     // 1/sqrt(64)
                if (diag && (j * 16 + r15 > myrow + r)) sv[j] = -1e30f;
            }
            float mx = fmaxf(fmaxf(sv[0], sv[1]), fmaxf(sv[2], sv[3]));
            mx = fmaxf(mx, __shfl_xor(mx, 1));
            mx = fmaxf(mx, __shfl_xor(mx, 2));
            mx = fmaxf(mx, __shfl_xor(mx, 4));
            mx = fmaxf(mx, __shfl_xor(mx, 8));
            const float mnew = fmaxf(mrow[r], mx);
            const float corr = __expf(mrow[r] - mnew);
            float rs = 0.f;
            #pragma unroll
            for (int j = 0; j < 4; ++j) {
                p[j][r] = __expf(sv[j] - mnew);
                rs += p[j][r];
            }
            rs += __shfl_xor(rs, 1);
            rs += __shfl_xor(rs, 2);
            rs += __shfl_xor(rs, 4);
            rs += __shfl_xor(rs, 8);
            lrow[r] = lrow[r] * corr + rs;
            mrow[r] = mnew;
            #pragma unroll
            for (int j2 = 0; j2 < 4; ++j2) po[j2][r] *= corr;
        }

        // ---- reshape P via per-wave LDS (C-layout -> A-frag layout) ----
        #pragma unroll
        for (int r = 0; r < 4; ++r)
            #pragma unroll
            for (int j = 0; j < 4; ++j)
                Ps[wid][g * 4 + r][j * 16 + r15] = p[j][r];
        // same-wave in-order DS: writes land before the reads below
        union { bf16x8 v; unsigned short u[8]; } pa0, pa1;
        {
            const float4 a = *(const float4*)&Ps[wid][r15][g * 8];
            const float4 c = *(const float4*)&Ps[wid][r15][g * 8 + 4];
            pa0.u[0] = f2bf(a.x); pa0.u[1] = f2bf(a.y); pa0.u[2] = f2bf(a.z); pa0.u[3] = f2bf(a.w);
            pa0.u[4] = f2bf(c.x); pa0.u[5] = f2bf(c.y); pa0.u[6] = f2bf(c.z); pa0.u[7] = f2bf(c.w);
            const float4 d = *(const float4*)&Ps[wid][r15][32 + g * 8];
            const float4 e = *(const float4*)&Ps[wid][r15][32 + g * 8 + 4];
            pa1.u[0] = f2bf(d.x); pa1.u[1] = f2bf(d.y); pa1.u[2] = f2bf(d.z); pa1.u[3] = f2bf(d.w);
            pa1.u[4] = f2bf(e.x); pa1.u[5] = f2bf(e.y); pa1.u[6] = f2bf(e.z); pa1.u[7] = f2bf(e.w);
        }

        // ---- O += P V : B-frag from Vs[d][key] ----
        #pragma unroll
        for (int j2 = 0; j2 < 4; ++j2) {
            const int vb0 = ((j2 * 16 + r15) * 128 + g * 16) ^ sw;
            const bf16x8 vf0 = *(const bf16x8*)((const char*)Vs + vb0);
            const bf16x8 vf1 = *(const bf16x8*)((const char*)Vs + (vb0 ^ 64));
            po[j2] = __builtin_amdgcn_mfma_f32_16x16x32_bf16(pa0.v, vf0, po[j2], 0, 0, 0);
            po[j2] = __builtin_amdgcn_mfma_f32_16x16x32_bf16(pa1.v, vf1, po[j2], 0, 0, 0);
        }
    }

    // ---- epilogue: Y[b, t, h*64 + d] bf16 ----
    float inv[4];
    #pragma unroll
    for (int r = 0; r < 4; ++r) inv[r] = 1.0f / lrow[r];
    #pragma unroll
    for (int j2 = 0; j2 < 4; ++j2)
        #pragma unroll
        for (int r = 0; r < 4; ++r) {
            const int t = qt * 64 + myrow + r;
            Y[((size_t)(b * T_ + t)) * C_ + h * 64 + j2 * 16 + r15] = f2bf(po[j2][r] * inv[r]);
        }
}

// ---------------------------------------------------------------------------
extern "C" void kernel_launch(void* const* d_in, const int* in_sizes, int n_in,
                              void* d_out, int out_size, void* d_ws, size_t ws_size,
                              hipStream_t stream)
{
    const float* x      = (const float*)d_in[0];
    const float* W_attn = (const float*)d_in[1];
    const float* b_attn = (const float*)d_in[2];
    const float* W_proj = (const float*)d_in[3];
    const float* b_proj = (const float*)d_in[4];
    float* out = (float*)d_out;

    const size_t NQ = (size_t)B_ * H_ * T_ * HD_;       // 4,194,304
    unsigned short* qbf = (unsigned short*)d_ws;        // bf16 [B,H,T,hd]
    unsigned short* kbf = qbf + NQ;                     // bf16 [B,H,T,hd]
    unsigned short* vt  = kbf + NQ;                     // bf16 [B,H,hd,T]
    unsigned short* yb  = vt  + NQ;                     // bf16 [B,T,C]
    unsigned short* xb  = yb  + NQ;                     // bf16 x [M][K]
    unsigned short* wat = xb  + NQ;                     // bf16 W_attn^T [3C][C]
    unsigned short* wpt = wat + (size_t)(3 * C_) * C_;  // bf16 W_proj^T [C][C]
    float2* ropetab = (float2*)(wpt + (size_t)C_ * C_); // fp32 [T][32] cos/sin
    // total ws ~ 50.9 MB

    // 0) casts / transposes / rope table
    castk<<<(int)(NQ / 4 / 256), 256, 0, stream>>>(x, xb, (int)(NQ / 4));
    transcast_k<<<dim3(3 * C_ / 32, C_ / 32), 256, 0, stream>>>(W_attn, wat, C_, 3 * C_);
    transcast_k<<<dim3(C_ / 32, C_ / 32), 256, 0, stream>>>(W_proj, wpt, C_, C_);
    rope_table_k<<<T_ * 32 / 256, 256, 0, stream>>>(ropetab);

    // 1) QKV GEMM + bias + RoPE(q,k) + head-split (q,k bf16; v bf16 transposed)
    mgemm<0><<<dim3(3 * C_ / 128, B_ * T_ / 128), 256, 0, stream>>>(
        xb, wat, b_attn, ropetab, qbf, kbf, vt, B_ * T_, 3 * C_, C_);

    // 2) MFMA causal attention -> yb (bf16). grid x=bh, y=qt (load balance)
    attn_mfma<<<dim3(B_ * H_, T_ / 64), 256, 0, stream>>>(qbf, kbf, vt, yb);

    // 3) output projection -> out fp32
    mgemm<1><<<dim3(C_ / 128, B_ * T_ / 128), 256, 0, stream>>>(
        yb, wpt, b_proj, nullptr, out, nullptr, nullptr, B_ * T_, C_, C_);
}

// Round 7
// 237.943 us; speedup vs baseline: 1.0653x; 1.0653x over previous
//
#include <hip/hip_runtime.h>
#include <math.h>

// Problem constants (B=2, T=2048, C=1024, H=16, hd=64)
#define B_  2
#define T_  2048
#define C_  1024
#define H_  16
#define HD_ 64

typedef __bf16 bf16x8 __attribute__((ext_vector_type(8)));
typedef float  f32x4  __attribute__((ext_vector_type(4)));

__device__ __forceinline__ unsigned short f2bf(float f) {
    unsigned int u = __float_as_uint(f);
    unsigned int r = (u + 0x7fffu + ((u >> 16) & 1u)) >> 16;   // RNE
    return (unsigned short)r;
}

// async global->LDS, 16B/lane. lds ptr must be WAVE-UNIFORM; HW adds lane*16.
__device__ __forceinline__ void async16(const void* g, void* l) {
    __builtin_amdgcn_global_load_lds(
        (const __attribute__((address_space(1))) unsigned int*)g,
        (__attribute__((address_space(3))) unsigned int*)l, 16, 0, 0);
}

// ---------------------------------------------------------------------------
// cast fp32 -> bf16, vectorized. n4 = n/4.
// ---------------------------------------------------------------------------
__global__ __launch_bounds__(256)
void castk(const float* __restrict__ in, unsigned short* __restrict__ out, int n4)
{
    const int i = blockIdx.x * 256 + threadIdx.x;
    if (i >= n4) return;
    const float4 v = ((const float4*)in)[i];
    ushort4 o;
    o.x = f2bf(v.x); o.y = f2bf(v.y); o.z = f2bf(v.z); o.w = f2bf(v.w);
    ((ushort4*)out)[i] = o;
}

// ---------------------------------------------------------------------------
// cast + transpose: in fp32 [K][N] -> out bf16 [N][K]. 32x32 LDS tiles.
// ---------------------------------------------------------------------------
__global__ __launch_bounds__(256)
void transcast_k(const float* __restrict__ in, unsigned short* __restrict__ out,
                 int K, int N)
{
    __shared__ float t[32][33];
    const int n0 = blockIdx.x * 32, k0 = blockIdx.y * 32;
    const int tx = threadIdx.x & 31, ty = threadIdx.x >> 5;
    #pragma unroll
    for (int r = 0; r < 4; ++r)
        t[ty + 8 * r][tx] = in[(size_t)(k0 + ty + 8 * r) * N + n0 + tx];
    __syncthreads();
    #pragma unroll
    for (int r = 0; r < 4; ++r)
        out[(size_t)(n0 + ty + 8 * r) * K + k0 + tx] = f2bf(t[tx][ty + 8 * r]);
}

// ---------------------------------------------------------------------------
// RoPE cos/sin table: tab[t*32+dd] = {cos(t*f_dd), sin(t*f_dd)}, fp32.
// ---------------------------------------------------------------------------
__global__ __launch_bounds__(256)
void rope_table_k(float2* __restrict__ tab)
{
    const int idx = blockIdx.x * 256 + threadIdx.x;   // 0 .. T_*32-1
    const int dd = idx & 31;
    const int t  = idx >> 5;
    const float invf = expf(-(float)dd * (9.210340371976184f / 32.0f)); // 10000^(-dd/32)
    float sn, cs;
    sincosf((float)t * invf, &sn, &cs);
    tab[idx] = make_float2(cs, sn);
}

// ---------------------------------------------------------------------------
// bf16 MFMA GEMM: 128x128 tile, BK=64, 4 waves (2x2 of 64x64), 4x4
// mfma_f32_16x16x32_bf16 frags/wave, global_load_lds(16B) staging with
// XOR-swizzled tiles (byte ^= (row&7)<<4; pre-swizzled global source).
// A bf16 [M][K], Bt bf16 [N][K], bias fp32 [N].
// MODE 0: q,k bf16 [B,H,T,hd] with RoPE fused; v bf16 [B,H,hd,T].
// MODE 1: out0 = fp32 [M][N].
// ---------------------------------------------------------------------------
template<int MODE>
__global__ __launch_bounds__(256)
void mgemm(const unsigned short* __restrict__ A, const unsigned short* __restrict__ Bt,
           const float* __restrict__ bias, const float2* __restrict__ rope,
           void* __restrict__ out0, void* __restrict__ out1, void* __restrict__ out2,
           int M, int N, int K)
{
    __shared__ __align__(16) unsigned short As[128 * 64];   // 16KB, 128B rows, swizzled
    __shared__ __align__(16) unsigned short Bs[128 * 64];

    const int tid  = threadIdx.x;
    const int lane = tid & 63;
    const int wid  = tid >> 6;
    const int m0 = blockIdx.y * 128;
    const int n0 = blockIdx.x * 128;
    const int wr = wid >> 1, wc = wid & 1;

    // staging: 8 lanes/row (16B chunks); wave covers rows wid*32 .. +32
    const int srow8 = lane >> 3;              // 0..7
    const int csrc  = (lane & 7) ^ srow8;     // inverse swizzle on global source
    const unsigned short* gA = A  + (size_t)(m0 + wid * 32 + srow8) * K + csrc * 8;
    const unsigned short* gB = Bt + (size_t)(n0 + wid * 32 + srow8) * K + csrc * 8;
    unsigned short* lA = As + wid * 32 * 64;  // wave-uniform LDS bases
    unsigned short* lB = Bs + wid * 32 * 64;

    f32x4 acc[4][4];
    #pragma unroll
    for (int i = 0; i < 4; ++i)
        #pragma unroll
        for (int j = 0; j < 4; ++j) acc[i][j] = (f32x4)0.f;

    const int r15 = lane & 15;
    const int g   = lane >> 4;                // 0..3
    const int sw  = (r15 & 7) << 4;           // read-side XOR swizzle (bytes)

    for (int kt = 0; kt < K; kt += 64) {
        __syncthreads();
        async16(gA + kt,          lA);
        async16(gA + kt +  8 * K, lA + 512);
        async16(gA + kt + 16 * K, lA + 1024);
        async16(gA + kt + 24 * K, lA + 1536);
        async16(gB + kt,          lB);
        async16(gB + kt +  8 * K, lB + 512);
        async16(gB + kt + 16 * K, lB + 1024);
        async16(gB + kt + 24 * K, lB + 1536);
        __syncthreads();

        #pragma unroll
        for (int kk = 0; kk < 2; ++kk) {
            bf16x8 af[4], bg[4];
            #pragma unroll
            for (int i = 0; i < 4; ++i)
                af[i] = *(const bf16x8*)((const char*)As +
                        ((((wr * 64 + i * 16 + r15) << 7) + (kk << 6) + (g << 4)) ^ sw));
            #pragma unroll
            for (int j = 0; j < 4; ++j)
                bg[j] = *(const bf16x8*)((const char*)Bs +
                        ((((wc * 64 + j * 16 + r15) << 7) + (kk << 6) + (g << 4)) ^ sw));
            #pragma unroll
            for (int i = 0; i < 4; ++i)
                #pragma unroll
                for (int j = 0; j < 4; ++j)
                    acc[i][j] = __builtin_amdgcn_mfma_f32_16x16x32_bf16(af[i], bg[j], acc[i][j], 0, 0, 0);
        }
    }

    // epilogue: C/D layout col=lane&15 (+j*16), row=(lane>>4)*4+reg  [m89]
    const int rg = g * 4;
    if (MODE == 0) {
        const int which = n0 >> 10;               // block-uniform: 0=q 1=k 2=v
        if (which < 2) {
            // ---- fused RoPE on fp32 accumulators, single bf16 rounding ----
            unsigned short* dst = (unsigned short*)(which == 0 ? out0 : out1);
            const int h = ((n0 & 1023) >> 6) + wc;    // head (uniform per wave)
            #pragma unroll
            for (int i = 0; i < 4; ++i) {
                #pragma unroll
                for (int r = 0; r < 4; ++r) {
                    const int row = m0 + wr * 64 + i * 16 + rg + r;
                    const int b = row >> 11, t = row & 2047;
                    const size_t obase = (((size_t)(b * H_ + h)) * T_ + t) * HD_;
                    #pragma unroll
                    for (int j = 0; j < 2; ++j) {
                        const int d1 = j * 16 + r15;          // 0..31
                        const float v1 = acc[i][j][r]     + bias[n0 + wc * 64 + d1];
                        const float v2 = acc[i][j + 2][r] + bias[n0 + wc * 64 + d1 + 32];
                        const float2 cssn = rope[t * 32 + d1];
                        dst[obase + d1]      = f2bf(v1 * cssn.x - v2 * cssn.y);
                        dst[obase + d1 + 32] = f2bf(v2 * cssn.x + v1 * cssn.y);
                    }
                }
            }
        } else {
            // ---- v: bias + transpose-scatter to [B,H,hd,T] ----
            #pragma unroll
            for (int j = 0; j < 4; ++j) {
                const int col = n0 + wc * 64 + j * 16 + r15;
                const float bv = bias[col];
                const int c = col & 1023;
                const int h = c >> 6, d = c & 63;
                #pragma unroll
                for (int i = 0; i < 4; ++i) {
                    #pragma unroll
                    for (int r = 0; r < 4; ++r) {
                        const int row = m0 + wr * 64 + i * 16 + rg + r;
                        const int b = row >> 11, t = row & 2047;
                        ((unsigned short*)out2)[(((size_t)(b * H_ + h)) * HD_ + d) * T_ + t]
                            = f2bf(acc[i][j][r] + bv);
                    }
                }
            }
        }
    } else {
        #pragma unroll
        for (int j = 0; j < 4; ++j) {
            const int col = n0 + wc * 64 + j * 16 + r15;
            const float bv = bias[col];
            #pragma unroll
            for (int i = 0; i < 4; ++i) {
                #pragma unroll
                for (int r = 0; r < 4; ++r) {
                    const int row = m0 + wr * 64 + i * 16 + rg + r;
                    ((float*)out0)[(size_t)row * N + col] = acc[i][j][r] + bv;
                }
            }
        }
    }
}

// ---------------------------------------------------------------------------
// MFMA flash attention, register-prefetch pipeline (T14).
// Block = 4 waves, one (bh, 64-row q-tile). Wave wid owns q-rows wid*16..+16.
// K bf16 [B,H,T,hd], Vt bf16 [B,H,hd,T] staged: global->regs (issued one tile
// ahead, latency hidden under compute) -> swizzled ds_write_b128.
// Per K-tile: 16 MFMA (8 QK^T + 8 PV); softmax via exp2 with folded scale.
// Causal balance: qt = {y0, 15-y0, 16+y0, 31-y0}[y>>3] so each CU's resident
// blocks sum to equal work.
// ---------------------------------------------------------------------------
__global__ __launch_bounds__(256)
void attn_mfma(const unsigned short* __restrict__ Q,
               const unsigned short* __restrict__ K,
               const unsigned short* __restrict__ Vt,
               unsigned short* __restrict__ Y)
{
    __shared__ __align__(16) unsigned short Ks[64 * 64];   // 8KB, swizzled
    __shared__ __align__(16) unsigned short Vs[64 * 64];   // 8KB, swizzled (rows = d)
    __shared__ float Ps[4][16][68];                        // per-wave P, padded

    const int tid  = threadIdx.x;
    const int lane = tid & 63;
    const int wid  = tid >> 6;
    const int bh   = blockIdx.x;               // 0..31
    const int y    = blockIdx.y;               // 0..31
    const int y0   = y & 7;
    const int yk   = y >> 3;
    const int qt   = (yk == 0) ? y0 : (yk == 1) ? (15 - y0)
                   : (yk == 2) ? (16 + y0) : (31 - y0);
    const int b    = bh >> 4, h = bh & 15;
    const int g    = lane >> 4;                // 0..3
    const int r15  = lane & 15;
    const int sw   = (r15 & 7) << 4;           // read-side XOR swizzle

    // staging: 8 lanes/row; lane -> row srow8 (0..7), chunk c8; swizzled write
    const int srow8 = lane >> 3;
    const int c8    = lane & 7;
    const int wsw   = (c8 ^ srow8) << 4;       // write-side swizzled chunk (bytes)

    const size_t qkbase = (size_t)bh * T_ * HD_;
    const unsigned short* gK = K  + qkbase + (size_t)(wid * 16 + srow8) * HD_ + c8 * 8;
    const unsigned short* gV = Vt + ((size_t)bh * HD_ + wid * 16 + srow8) * T_ + c8 * 8;
    char* lK = (char*)Ks + (wid * 16 + srow8) * 128 + wsw;
    char* lV = (char*)Vs + (wid * 16 + srow8) * 128 + wsw;

    // Q fragments (A-operand): m = r15 (q-row), k = d
    const int qrow = qt * 64 + wid * 16 + r15;
    const unsigned short* qp = Q + qkbase + (size_t)qrow * HD_ + g * 8;
    const bf16x8 qf0 = *(const bf16x8*)(qp);
    const bf16x8 qf1 = *(const bf16x8*)(qp + 32);

    f32x4 po[4];
    float mrow[4], lrow[4];
    #pragma unroll
    for (int j = 0; j < 4; ++j) po[j] = (f32x4)0.f;
    #pragma unroll
    for (int r = 0; r < 4; ++r) { mrow[r] = -1e30f; lrow[r] = 0.f; }

    const int myrow = wid * 16 + g * 4;        // q-row (in tile) of acc reg r=0
    const float C2 = 0.18033688011112042f;     // 0.125 * log2(e)

    // prologue: prefetch tile 0 into registers
    uint4 kr0 = *(const uint4*)(gK);
    uint4 kr1 = *(const uint4*)(gK + 8 * HD_);
    uint4 vr0 = *(const uint4*)(gV);
    uint4 vr1 = *(const uint4*)(gV + 8 * T_);

    for (int kt = 0; kt <= qt; ++kt) {
        // stage current tile regs -> swizzled LDS (prev compute done: barrier2)
        *(uint4*)(lK)           = kr0;
        *(uint4*)(lK + 8 * 128) = kr1;
        *(uint4*)(lV)           = vr0;
        *(uint4*)(lV + 8 * 128) = vr1;
        __syncthreads();                       // tiles visible to all waves

        // prefetch next tile (latency hides under compute below)
        if (kt < qt) {
            const size_t ko = (size_t)(kt + 1) * 64;
            kr0 = *(const uint4*)(gK + ko * HD_);
            kr1 = *(const uint4*)(gK + ko * HD_ + 8 * HD_);
            vr0 = *(const uint4*)(gV + ko);
            vr1 = *(const uint4*)(gV + ko + 8 * T_);
        }

        // ---- S = Q K^T : B-frag from Ks[key][d] ----
        f32x4 sa[4];
        #pragma unroll
        for (int j = 0; j < 4; ++j) sa[j] = (f32x4)0.f;
        #pragma unroll
        for (int j = 0; j < 4; ++j) {
            const int kb0 = ((j * 16 + r15) * 128 + g * 16) ^ sw;
            const bf16x8 kf0 = *(const bf16x8*)((const char*)Ks + kb0);
            const bf16x8 kf1 = *(const bf16x8*)((const char*)Ks + (kb0 ^ 64));
            sa[j] = __builtin_amdgcn_mfma_f32_16x16x32_bf16(qf0, kf0, sa[j], 0, 0, 0);
            sa[j] = __builtin_amdgcn_mfma_f32_16x16x32_bf16(qf1, kf1, sa[j], 0, 0, 0);
        }

        // ---- online softmax in exp2 domain (scale folded) ----
        const bool diag = (kt == qt);
        float p[4][4];
        #pragma unroll
        for (int r = 0; r < 4; ++r) {
            float sc[4];
            #pragma unroll
            for (int j = 0; j < 4; ++j) sc[j] = sa[j][r] * C2;
            if (diag) {                        // uniform branch: only last tile
                #pragma unroll
                for (int j = 0; j < 4; ++j)
                    if (j * 16 + r15 > myrow + r) sc[j] = -1e30f;
            }
            float mx = fmaxf(fmaxf(sc[0], sc[1]), fmaxf(sc[2], sc[3]));
            mx = fmaxf(mx, __shfl_xor(mx, 1));
            mx = fmaxf(mx, __shfl_xor(mx, 2));
            mx = fmaxf(mx, __shfl_xor(mx, 4));
            mx = fmaxf(mx, __shfl_xor(mx, 8));
            const float mnew = fmaxf(mrow[r], mx);
            const float corr = exp2f(mrow[r] - mnew);
            float rs = 0.f;
            #pragma unroll
            for (int j = 0; j < 4; ++j) {
                p[j][r] = exp2f(sc[j] - mnew);
                rs += p[j][r];
            }
            rs += __shfl_xor(rs, 1);
            rs += __shfl_xor(rs, 2);
            rs += __shfl_xor(rs, 4);
            rs += __shfl_xor(rs, 8);
            lrow[r] = lrow[r] * corr + rs;
            mrow[r] = mnew;
            #pragma unroll
            for (int j2 = 0; j2 < 4; ++j2) po[j2][r] *= corr;
        }

        // ---- reshape P via per-wave LDS (C-layout -> A-frag layout) ----
        #pragma unroll
        for (int r = 0; r < 4; ++r)
            #pragma unroll
            for (int j = 0; j < 4; ++j)
                Ps[wid][g * 4 + r][j * 16 + r15] = p[j][r];
        // same-wave in-order DS: writes land before the reads below
        union { bf16x8 v; unsigned short u[8]; } pa0, pa1;
        {
            const float4 a = *(const float4*)&Ps[wid][r15][g * 8];
            const float4 c = *(const float4*)&Ps[wid][r15][g * 8 + 4];
            pa0.u[0] = f2bf(a.x); pa0.u[1] = f2bf(a.y); pa0.u[2] = f2bf(a.z); pa0.u[3] = f2bf(a.w);
            pa0.u[4] = f2bf(c.x); pa0.u[5] = f2bf(c.y); pa0.u[6] = f2bf(c.z); pa0.u[7] = f2bf(c.w);
            const float4 d = *(const float4*)&Ps[wid][r15][32 + g * 8];
            const float4 e = *(const float4*)&Ps[wid][r15][32 + g * 8 + 4];
            pa1.u[0] = f2bf(d.x); pa1.u[1] = f2bf(d.y); pa1.u[2] = f2bf(d.z); pa1.u[3] = f2bf(d.w);
            pa1.u[4] = f2bf(e.x); pa1.u[5] = f2bf(e.y); pa1.u[6] = f2bf(e.z); pa1.u[7] = f2bf(e.w);
        }

        // ---- O += P V : B-frag from Vs[d][key] ----
        #pragma unroll
        for (int j2 = 0; j2 < 4; ++j2) {
            const int vb0 = ((j2 * 16 + r15) * 128 + g * 16) ^ sw;
            const bf16x8 vf0 = *(const bf16x8*)((const char*)Vs + vb0);
            const bf16x8 vf1 = *(const bf16x8*)((const char*)Vs + (vb0 ^ 64));
            po[j2] = __builtin_amdgcn_mfma_f32_16x16x32_bf16(pa0.v, vf0, po[j2], 0, 0, 0);
            po[j2] = __builtin_amdgcn_mfma_f32_16x16x32_bf16(pa1.v, vf1, po[j2], 0, 0, 0);
        }

        __syncthreads();                       // all waves done reading Ks/Vs
    }

    // ---- epilogue: Y[b, t, h*64 + d] bf16 ----
    float inv[4];
    #pragma unroll
    for (int r = 0; r < 4; ++r) inv[r] = 1.0f / lrow[r];
    #pragma unroll
    for (int j2 = 0; j2 < 4; ++j2)
        #pragma unroll
        for (int r = 0; r < 4; ++r) {
            const int t = qt * 64 + myrow + r;
            Y[((size_t)(b * T_ + t)) * C_ + h * 64 + j2 * 16 + r15] = f2bf(po[j2][r] * inv[r]);
        }
}

// ---------------------------------------------------------------------------
extern "C" void kernel_launch(void* const* d_in, const int* in_sizes, int n_in,
                              void* d_out, int out_size, void* d_ws, size_t ws_size,
                              hipStream_t stream)
{
    const float* x      = (const float*)d_in[0];
    const float* W_attn = (const float*)d_in[1];
    const float* b_attn = (const float*)d_in[2];
    const float* W_proj = (const float*)d_in[3];
    const float* b_proj = (const float*)d_in[4];
    float* out = (float*)d_out;

    const size_t NQ = (size_t)B_ * H_ * T_ * HD_;       // 4,194,304
    unsigned short* qbf = (unsigned short*)d_ws;        // bf16 [B,H,T,hd]
    unsigned short* kbf = qbf + NQ;                     // bf16 [B,H,T,hd]
    unsigned short* vt  = kbf + NQ;                     // bf16 [B,H,hd,T]
    unsigned short* yb  = vt  + NQ;                     // bf16 [B,T,C]
    unsigned short* xb  = yb  + NQ;                     // bf16 x [M][K]
    unsigned short* wat = xb  + NQ;                     // bf16 W_attn^T [3C][C]
    unsigned short* wpt = wat + (size_t)(3 * C_) * C_;  // bf16 W_proj^T [C][C]
    float2* ropetab = (float2*)(wpt + (size_t)C_ * C_); // fp32 [T][32] cos/sin
    // total ws ~ 50.9 MB

    // 0) casts / transposes / rope table
    castk<<<(int)(NQ / 4 / 256), 256, 0, stream>>>(x, xb, (int)(NQ / 4));
    transcast_k<<<dim3(3 * C_ / 32, C_ / 32), 256, 0, stream>>>(W_attn, wat, C_, 3 * C_);
    transcast_k<<<dim3(C_ / 32, C_ / 32), 256, 0, stream>>>(W_proj, wpt, C_, C_);
    rope_table_k<<<T_ * 32 / 256, 256, 0, stream>>>(ropetab);

    // 1) QKV GEMM + bias + RoPE(q,k) + head-split (q,k bf16; v bf16 transposed)
    mgemm<0><<<dim3(3 * C_ / 128, B_ * T_ / 128), 256, 0, stream>>>(
        xb, wat, b_attn, ropetab, qbf, kbf, vt, B_ * T_, 3 * C_, C_);

    // 2) MFMA causal attention -> yb (bf16). grid x=bh, y->qt balanced map
    attn_mfma<<<dim3(B_ * H_, T_ / 64), 256, 0, stream>>>(qbf, kbf, vt, yb);

    // 3) output projection -> out fp32
    mgemm<1><<<dim3(C_ / 128, B_ * T_ / 128), 256, 0, stream>>>(
        yb, wpt, b_proj, nullptr, out, nullptr, nullptr, B_ * T_, C_, C_);
}

// Round 8
// 218.026 us; speedup vs baseline: 1.1626x; 1.0913x over previous
//
#include <hip/hip_runtime.h>
#include <math.h>

// Problem constants (B=2, T=2048, C=1024, H=16, hd=64)
#define B_  2
#define T_  2048
#define C_  1024
#define H_  16
#define HD_ 64

typedef __bf16 bf16x8 __attribute__((ext_vector_type(8)));
typedef float  f32x4  __attribute__((ext_vector_type(4)));

__device__ __forceinline__ unsigned short f2bf(float f) {
    unsigned int u = __float_as_uint(f);
    unsigned int r = (u + 0x7fffu + ((u >> 16) & 1u)) >> 16;   // RNE
    return (unsigned short)r;
}

// async global->LDS, 16B/lane. lds ptr must be WAVE-UNIFORM; HW adds lane*16.
__device__ __forceinline__ void async16(const void* g, void* l) {
    __builtin_amdgcn_global_load_lds(
        (const __attribute__((address_space(1))) unsigned int*)g,
        (__attribute__((address_space(3))) unsigned int*)l, 16, 0, 0);
}

// ---------------------------------------------------------------------------
// cast fp32 -> bf16, vectorized. n4 = n/4.
// ---------------------------------------------------------------------------
__global__ __launch_bounds__(256)
void castk(const float* __restrict__ in, unsigned short* __restrict__ out, int n4)
{
    const int i = blockIdx.x * 256 + threadIdx.x;
    if (i >= n4) return;
    const float4 v = ((const float4*)in)[i];
    ushort4 o;
    o.x = f2bf(v.x); o.y = f2bf(v.y); o.z = f2bf(v.z); o.w = f2bf(v.w);
    ((ushort4*)out)[i] = o;
}

// ---------------------------------------------------------------------------
// cast + transpose: in fp32 [K][N] -> out bf16 [N][K]. 32x32 LDS tiles.
// ---------------------------------------------------------------------------
__global__ __launch_bounds__(256)
void transcast_k(const float* __restrict__ in, unsigned short* __restrict__ out,
                 int K, int N)
{
    __shared__ float t[32][33];
    const int n0 = blockIdx.x * 32, k0 = blockIdx.y * 32;
    const int tx = threadIdx.x & 31, ty = threadIdx.x >> 5;
    #pragma unroll
    for (int r = 0; r < 4; ++r)
        t[ty + 8 * r][tx] = in[(size_t)(k0 + ty + 8 * r) * N + n0 + tx];
    __syncthreads();
    #pragma unroll
    for (int r = 0; r < 4; ++r)
        out[(size_t)(n0 + ty + 8 * r) * K + k0 + tx] = f2bf(t[tx][ty + 8 * r]);
}

// ---------------------------------------------------------------------------
// RoPE cos/sin table: tab[t*32+dd] = {cos(t*f_dd), sin(t*f_dd)}, fp32.
// ---------------------------------------------------------------------------
__global__ __launch_bounds__(256)
void rope_table_k(float2* __restrict__ tab)
{
    const int idx = blockIdx.x * 256 + threadIdx.x;   // 0 .. T_*32-1
    const int dd = idx & 31;
    const int t  = idx >> 5;
    const float invf = expf(-(float)dd * (9.210340371976184f / 32.0f)); // 10000^(-dd/32)
    float sn, cs;
    sincosf((float)t * invf, &sn, &cs);
    tab[idx] = make_float2(cs, sn);
}

// ---------------------------------------------------------------------------
// bf16 MFMA GEMM: 128x128 tile, BK=64, 4 waves (2x2 of 64x64), 4x4
// mfma_f32_16x16x32_bf16 frags/wave, global_load_lds(16B) staging with
// XOR-swizzled tiles (byte ^= (row&7)<<4; pre-swizzled global source).
// A bf16 [M][K], Bt bf16 [N][K], bias fp32 [N].
// MODE 0: q,k bf16 [B,H,T,hd] with RoPE fused; v bf16 [B,H,hd,T].
// MODE 1: out0 = fp32 [M][N].
// ---------------------------------------------------------------------------
template<int MODE>
__global__ __launch_bounds__(256)
void mgemm(const unsigned short* __restrict__ A, const unsigned short* __restrict__ Bt,
           const float* __restrict__ bias, const float2* __restrict__ rope,
           void* __restrict__ out0, void* __restrict__ out1, void* __restrict__ out2,
           int M, int N, int K)
{
    __shared__ __align__(16) unsigned short As[128 * 64];   // 16KB, 128B rows, swizzled
    __shared__ __align__(16) unsigned short Bs[128 * 64];

    const int tid  = threadIdx.x;
    const int lane = tid & 63;
    const int wid  = tid >> 6;
    const int m0 = blockIdx.y * 128;
    const int n0 = blockIdx.x * 128;
    const int wr = wid >> 1, wc = wid & 1;

    // staging: 8 lanes/row (16B chunks); wave covers rows wid*32 .. +32
    const int srow8 = lane >> 3;              // 0..7
    const int csrc  = (lane & 7) ^ srow8;     // inverse swizzle on global source
    const unsigned short* gA = A  + (size_t)(m0 + wid * 32 + srow8) * K + csrc * 8;
    const unsigned short* gB = Bt + (size_t)(n0 + wid * 32 + srow8) * K + csrc * 8;
    unsigned short* lA = As + wid * 32 * 64;  // wave-uniform LDS bases
    unsigned short* lB = Bs + wid * 32 * 64;

    f32x4 acc[4][4];
    #pragma unroll
    for (int i = 0; i < 4; ++i)
        #pragma unroll
        for (int j = 0; j < 4; ++j) acc[i][j] = (f32x4)0.f;

    const int r15 = lane & 15;
    const int g   = lane >> 4;                // 0..3
    const int sw  = (r15 & 7) << 4;           // read-side XOR swizzle (bytes)

    for (int kt = 0; kt < K; kt += 64) {
        __syncthreads();
        async16(gA + kt,          lA);
        async16(gA + kt +  8 * K, lA + 512);
        async16(gA + kt + 16 * K, lA + 1024);
        async16(gA + kt + 24 * K, lA + 1536);
        async16(gB + kt,          lB);
        async16(gB + kt +  8 * K, lB + 512);
        async16(gB + kt + 16 * K, lB + 1024);
        async16(gB + kt + 24 * K, lB + 1536);
        __syncthreads();

        #pragma unroll
        for (int kk = 0; kk < 2; ++kk) {
            bf16x8 af[4], bg[4];
            #pragma unroll
            for (int i = 0; i < 4; ++i)
                af[i] = *(const bf16x8*)((const char*)As +
                        ((((wr * 64 + i * 16 + r15) << 7) + (kk << 6) + (g << 4)) ^ sw));
            #pragma unroll
            for (int j = 0; j < 4; ++j)
                bg[j] = *(const bf16x8*)((const char*)Bs +
                        ((((wc * 64 + j * 16 + r15) << 7) + (kk << 6) + (g << 4)) ^ sw));
            #pragma unroll
            for (int i = 0; i < 4; ++i)
                #pragma unroll
                for (int j = 0; j < 4; ++j)
                    acc[i][j] = __builtin_amdgcn_mfma_f32_16x16x32_bf16(af[i], bg[j], acc[i][j], 0, 0, 0);
        }
    }

    // epilogue: C/D layout col=lane&15 (+j*16), row=(lane>>4)*4+reg  [m89]
    const int rg = g * 4;
    if (MODE == 0) {
        const int which = n0 >> 10;               // block-uniform: 0=q 1=k 2=v
        if (which < 2) {
            // ---- fused RoPE on fp32 accumulators, single bf16 rounding ----
            unsigned short* dst = (unsigned short*)(which == 0 ? out0 : out1);
            const int h = ((n0 & 1023) >> 6) + wc;    // head (uniform per wave)
            #pragma unroll
            for (int i = 0; i < 4; ++i) {
                #pragma unroll
                for (int r = 0; r < 4; ++r) {
                    const int row = m0 + wr * 64 + i * 16 + rg + r;
                    const int b = row >> 11, t = row & 2047;
                    const size_t obase = (((size_t)(b * H_ + h)) * T_ + t) * HD_;
                    #pragma unroll
                    for (int j = 0; j < 2; ++j) {
                        const int d1 = j * 16 + r15;          // 0..31
                        const float v1 = acc[i][j][r]     + bias[n0 + wc * 64 + d1];
                        const float v2 = acc[i][j + 2][r] + bias[n0 + wc * 64 + d1 + 32];
                        const float2 cssn = rope[t * 32 + d1];
                        dst[obase + d1]      = f2bf(v1 * cssn.x - v2 * cssn.y);
                        dst[obase + d1 + 32] = f2bf(v2 * cssn.x + v1 * cssn.y);
                    }
                }
            }
        } else {
            // ---- v: bias + transpose-scatter to [B,H,hd,T] ----
            #pragma unroll
            for (int j = 0; j < 4; ++j) {
                const int col = n0 + wc * 64 + j * 16 + r15;
                const float bv = bias[col];
                const int c = col & 1023;
                const int h = c >> 6, d = c & 63;
                #pragma unroll
                for (int i = 0; i < 4; ++i) {
                    #pragma unroll
                    for (int r = 0; r < 4; ++r) {
                        const int row = m0 + wr * 64 + i * 16 + rg + r;
                        const int b = row >> 11, t = row & 2047;
                        ((unsigned short*)out2)[(((size_t)(b * H_ + h)) * HD_ + d) * T_ + t]
                            = f2bf(acc[i][j][r] + bv);
                    }
                }
            }
        }
    } else {
        #pragma unroll
        for (int j = 0; j < 4; ++j) {
            const int col = n0 + wc * 64 + j * 16 + r15;
            const float bv = bias[col];
            #pragma unroll
            for (int i = 0; i < 4; ++i) {
                #pragma unroll
                for (int r = 0; r < 4; ++r) {
                    const int row = m0 + wr * 64 + i * 16 + rg + r;
                    ((float*)out0)[(size_t)row * N + col] = acc[i][j][r] + bv;
                }
            }
        }
    }
}

// ---------------------------------------------------------------------------
// MFMA flash attention with SWAPPED QK^T (in-register softmax).
// Block = 4 waves, one (bh, 64-row q-tile). Wave wid owns q-rows wid*16..+16.
// QK^T computed as mfma(K_frag, Q_frag) -> lane holds S[key=jb*16+g*4+r][q=r15]:
// one q-row per lane, 16 keys in regs. Row softmax = in-reg tree + 2 shfl_xor
// (16,32) across the 4 g-groups; running m/l are SCALARS per lane (row r15).
// Rescale corr / final 1/l fetched for the PV-acc rows (g*4+r) via 4 bpermutes.
// P round-trips through per-wave Ps[q][key] (write: 4x ds_write_b128 at row
// r15; read path unchanged). PV unchanged. K/V reg-prefetch staging retained.
// ---------------------------------------------------------------------------
__global__ __launch_bounds__(256)
void attn_mfma(const unsigned short* __restrict__ Q,
               const unsigned short* __restrict__ K,
               const unsigned short* __restrict__ Vt,
               unsigned short* __restrict__ Y)
{
    __shared__ __align__(16) unsigned short Ks[64 * 64];   // 8KB, swizzled
    __shared__ __align__(16) unsigned short Vs[64 * 64];   // 8KB, swizzled (rows = d)
    __shared__ float Ps[4][16][68];                        // per-wave P[q][key], padded

    const int tid  = threadIdx.x;
    const int lane = tid & 63;
    const int wid  = tid >> 6;
    const int bh   = blockIdx.x;               // 0..31
    const int y    = blockIdx.y;               // 0..31
    const int y0   = y & 7;
    const int yk   = y >> 3;
    const int qt   = (yk == 0) ? y0 : (yk == 1) ? (15 - y0)
                   : (yk == 2) ? (16 + y0) : (31 - y0);
    const int b    = bh >> 4, h = bh & 15;
    const int g    = lane >> 4;                // 0..3
    const int r15  = lane & 15;
    const int g4   = g * 4;
    const int sw   = (r15 & 7) << 4;           // read-side XOR swizzle

    // staging: 8 lanes/row; lane -> row srow8 (0..7), chunk c8; swizzled write
    const int srow8 = lane >> 3;
    const int c8    = lane & 7;
    const int wsw   = (c8 ^ srow8) << 4;       // write-side swizzled chunk (bytes)

    const size_t qkbase = (size_t)bh * T_ * HD_;
    const unsigned short* gK = K  + qkbase + (size_t)(wid * 16 + srow8) * HD_ + c8 * 8;
    const unsigned short* gV = Vt + ((size_t)bh * HD_ + wid * 16 + srow8) * T_ + c8 * 8;
    char* lK = (char*)Ks + (wid * 16 + srow8) * 128 + wsw;
    char* lV = (char*)Vs + (wid * 16 + srow8) * 128 + wsw;

    // Q fragments: row = r15 (q-row), k = d  (used as the B-operand now)
    const int qrow = qt * 64 + wid * 16 + r15;
    const unsigned short* qp = Q + qkbase + (size_t)qrow * HD_ + g * 8;
    const bf16x8 qf0 = *(const bf16x8*)(qp);
    const bf16x8 qf1 = *(const bf16x8*)(qp + 32);

    f32x4 po[4];
    #pragma unroll
    for (int j = 0; j < 4; ++j) po[j] = (f32x4)0.f;
    float mrow = -1e30f, lrow = 0.f;           // stats for q-row r15 (scalar!)

    const int myrow = wid * 16 + g4;           // q-row (in tile) of PV-acc reg r=0
    const float C2 = 0.18033688011112042f;     // 0.125 * log2(e)

    // prologue: prefetch tile 0 into registers
    uint4 kr0 = *(const uint4*)(gK);
    uint4 kr1 = *(const uint4*)(gK + 8 * HD_);
    uint4 vr0 = *(const uint4*)(gV);
    uint4 vr1 = *(const uint4*)(gV + 8 * T_);

    for (int kt = 0; kt <= qt; ++kt) {
        // stage current tile regs -> swizzled LDS (prev compute done: barrier2)
        *(uint4*)(lK)           = kr0;
        *(uint4*)(lK + 8 * 128) = kr1;
        *(uint4*)(lV)           = vr0;
        *(uint4*)(lV + 8 * 128) = vr1;
        __syncthreads();                       // tiles visible to all waves

        // prefetch next tile (latency hides under compute below)
        if (kt < qt) {
            const size_t ko = (size_t)(kt + 1) * 64;
            kr0 = *(const uint4*)(gK + ko * HD_);
            kr1 = *(const uint4*)(gK + ko * HD_ + 8 * HD_);
            vr0 = *(const uint4*)(gV + ko);
            vr1 = *(const uint4*)(gV + ko + 8 * T_);
        }

        // ---- S^T = K Q^T : mfma(K_frag, Q_frag) -> D[key][q] ----
        f32x4 sa[4];
        #pragma unroll
        for (int jb = 0; jb < 4; ++jb) sa[jb] = (f32x4)0.f;
        #pragma unroll
        for (int jb = 0; jb < 4; ++jb) {
            const int kb0 = ((jb * 16 + r15) * 128 + g * 16) ^ sw;
            const bf16x8 kf0 = *(const bf16x8*)((const char*)Ks + kb0);
            const bf16x8 kf1 = *(const bf16x8*)((const char*)Ks + (kb0 ^ 64));
            sa[jb] = __builtin_amdgcn_mfma_f32_16x16x32_bf16(kf0, qf0, sa[jb], 0, 0, 0);
            sa[jb] = __builtin_amdgcn_mfma_f32_16x16x32_bf16(kf1, qf1, sa[jb], 0, 0, 0);
        }

        // ---- in-register online softmax (lane owns q-row r15, 16 keys) ----
        const bool diag = (kt == qt);
        float p[4][4];                         // p[jb][r]: key jb*16+g4+r
        {
            float sc[4][4];
            #pragma unroll
            for (int jb = 0; jb < 4; ++jb)
                #pragma unroll
                for (int r = 0; r < 4; ++r) {
                    float v = sa[jb][r] * C2;
                    if (diag && (jb * 16 + g4 + r > wid * 16 + r15)) v = -1e30f;
                    sc[jb][r] = v;
                }
            float m01 = fmaxf(fmaxf(sc[0][0], sc[0][1]), fmaxf(sc[0][2], sc[0][3]));
            float m11 = fmaxf(fmaxf(sc[1][0], sc[1][1]), fmaxf(sc[1][2], sc[1][3]));
            float m21 = fmaxf(fmaxf(sc[2][0], sc[2][1]), fmaxf(sc[2][2], sc[2][3]));
            float m31 = fmaxf(fmaxf(sc[3][0], sc[3][1]), fmaxf(sc[3][2], sc[3][3]));
            float mx  = fmaxf(fmaxf(m01, m11), fmaxf(m21, m31));
            mx = fmaxf(mx, __shfl_xor(mx, 16));
            mx = fmaxf(mx, __shfl_xor(mx, 32));
            const float mnew = fmaxf(mrow, mx);
            const float corr = exp2f(mrow - mnew);
            mrow = mnew;
            float rs = 0.f;
            #pragma unroll
            for (int jb = 0; jb < 4; ++jb)
                #pragma unroll
                for (int r = 0; r < 4; ++r) {
                    p[jb][r] = exp2f(sc[jb][r] - mnew);
                    rs += p[jb][r];
                }
            rs += __shfl_xor(rs, 16);
            rs += __shfl_xor(rs, 32);
            lrow = lrow * corr + rs;
            // fetch corr for the PV-acc rows (g4+r) from their owner lanes
            float cr[4];
            #pragma unroll
            for (int r = 0; r < 4; ++r) cr[r] = __shfl(corr, g4 + r, 64);
            #pragma unroll
            for (int j2 = 0; j2 < 4; ++j2)
                #pragma unroll
                for (int r = 0; r < 4; ++r) po[j2][r] *= cr[r];
        }

        // ---- P -> Ps[q][key]: 4x vectorized writes at row r15 ----
        #pragma unroll
        for (int jb = 0; jb < 4; ++jb)
            *(float4*)&Ps[wid][r15][jb * 16 + g4]
                = make_float4(p[jb][0], p[jb][1], p[jb][2], p[jb][3]);
        // same-wave in-order DS: writes land before the reads below
        union { bf16x8 v; unsigned short u[8]; } pa0, pa1;
        {
            const float4 a = *(const float4*)&Ps[wid][r15][g * 8];
            const float4 c = *(const float4*)&Ps[wid][r15][g * 8 + 4];
            pa0.u[0] = f2bf(a.x); pa0.u[1] = f2bf(a.y); pa0.u[2] = f2bf(a.z); pa0.u[3] = f2bf(a.w);
            pa0.u[4] = f2bf(c.x); pa0.u[5] = f2bf(c.y); pa0.u[6] = f2bf(c.z); pa0.u[7] = f2bf(c.w);
            const float4 d = *(const float4*)&Ps[wid][r15][32 + g * 8];
            const float4 e = *(const float4*)&Ps[wid][r15][32 + g * 8 + 4];
            pa1.u[0] = f2bf(d.x); pa1.u[1] = f2bf(d.y); pa1.u[2] = f2bf(d.z); pa1.u[3] = f2bf(d.w);
            pa1.u[4] = f2bf(e.x); pa1.u[5] = f2bf(e.y); pa1.u[6] = f2bf(e.z); pa1.u[7] = f2bf(e.w);
        }

        // ---- O += P V : B-frag from Vs[d][key] ----
        #pragma unroll
        for (int j2 = 0; j2 < 4; ++j2) {
            const int vb0 = ((j2 * 16 + r15) * 128 + g * 16) ^ sw;
            const bf16x8 vf0 = *(const bf16x8*)((const char*)Vs + vb0);
            const bf16x8 vf1 = *(const bf16x8*)((const char*)Vs + (vb0 ^ 64));
            po[j2] = __builtin_amdgcn_mfma_f32_16x16x32_bf16(pa0.v, vf0, po[j2], 0, 0, 0);
            po[j2] = __builtin_amdgcn_mfma_f32_16x16x32_bf16(pa1.v, vf1, po[j2], 0, 0, 0);
        }

        __syncthreads();                       // all waves done reading Ks/Vs
    }

    // ---- epilogue: Y[b, t, h*64 + d] bf16 ----
    const float linv = 1.0f / lrow;            // for q-row r15
    float inv[4];
    #pragma unroll
    for (int r = 0; r < 4; ++r) inv[r] = __shfl(linv, g4 + r, 64);
    #pragma unroll
    for (int j2 = 0; j2 < 4; ++j2)
        #pragma unroll
        for (int r = 0; r < 4; ++r) {
            const int t = qt * 64 + myrow + r;
            Y[((size_t)(b * T_ + t)) * C_ + h * 64 + j2 * 16 + r15] = f2bf(po[j2][r] * inv[r]);
        }
}

// ---------------------------------------------------------------------------
extern "C" void kernel_launch(void* const* d_in, const int* in_sizes, int n_in,
                              void* d_out, int out_size, void* d_ws, size_t ws_size,
                              hipStream_t stream)
{
    const float* x      = (const float*)d_in[0];
    const float* W_attn = (const float*)d_in[1];
    const float* b_attn = (const float*)d_in[2];
    const float* W_proj = (const float*)d_in[3];
    const float* b_proj = (const float*)d_in[4];
    float* out = (float*)d_out;

    const size_t NQ = (size_t)B_ * H_ * T_ * HD_;       // 4,194,304
    unsigned short* qbf = (unsigned short*)d_ws;        // bf16 [B,H,T,hd]
    unsigned short* kbf = qbf + NQ;                     // bf16 [B,H,T,hd]
    unsigned short* vt  = kbf + NQ;                     // bf16 [B,H,hd,T]
    unsigned short* yb  = vt  + NQ;                     // bf16 [B,T,C]
    unsigned short* xb  = yb  + NQ;                     // bf16 x [M][K]
    unsigned short* wat = xb  + NQ;                     // bf16 W_attn^T [3C][C]
    unsigned short* wpt = wat + (size_t)(3 * C_) * C_;  // bf16 W_proj^T [C][C]
    float2* ropetab = (float2*)(wpt + (size_t)C_ * C_); // fp32 [T][32] cos/sin
    // total ws ~ 50.9 MB

    // 0) casts / transposes / rope table
    castk<<<(int)(NQ / 4 / 256), 256, 0, stream>>>(x, xb, (int)(NQ / 4));
    transcast_k<<<dim3(3 * C_ / 32, C_ / 32), 256, 0, stream>>>(W_attn, wat, C_, 3 * C_);
    transcast_k<<<dim3(C_ / 32, C_ / 32), 256, 0, stream>>>(W_proj, wpt, C_, C_);
    rope_table_k<<<T_ * 32 / 256, 256, 0, stream>>>(ropetab);

    // 1) QKV GEMM + bias + RoPE(q,k) + head-split (q,k bf16; v bf16 transposed)
    mgemm<0><<<dim3(3 * C_ / 128, B_ * T_ / 128), 256, 0, stream>>>(
        xb, wat, b_attn, ropetab, qbf, kbf, vt, B_ * T_, 3 * C_, C_);

    // 2) MFMA causal attention -> yb (bf16). grid x=bh, y->qt balanced map
    attn_mfma<<<dim3(B_ * H_, T_ / 64), 256, 0, stream>>>(qbf, kbf, vt, yb);

    // 3) output projection -> out fp32
    mgemm<1><<<dim3(C_ / 128, B_ * T_ / 128), 256, 0, stream>>>(
        yb, wpt, b_proj, nullptr, out, nullptr, nullptr, B_ * T_, C_, C_);
}